// Round 1
// baseline (628.980 us; speedup 1.0000x reference)
//
#include <hip/hip_runtime.h>
#include <stdint.h>

// Problem constants
#define CDIM   128
#define NSEQ   2048            // sequences per direction (B*H or B*W)
#define TLEN   64
#define PIXTOT (32*64*64)      // 131072 pixels
#define OUTSZ  (32*128*64*64)  // 16777216 elements per output tensor

typedef short bf16x8 __attribute__((ext_vector_type(8)));  // 8 bf16 = 4 VGPRs
typedef float f32x4  __attribute__((ext_vector_type(4)));

__device__ __forceinline__ uint16_t f2bf(float f) {
  union { float f; uint32_t u; } v; v.f = f;
  uint32_t u = v.u;
  u += 0x7fffu + ((u >> 16) & 1u);   // round-to-nearest-even
  return (uint16_t)(u >> 16);
}

__device__ __forceinline__ float sigf(float x) {
  return __builtin_amdgcn_rcpf(1.f + __expf(-x));
}
__device__ __forceinline__ float tanh_(float x) {
  float ax = fabsf(x);
  float e  = __expf(-2.f * ax);
  float t  = (1.f - e) * __builtin_amdgcn_rcpf(1.f + e);
  return copysignf(t, x);
}

// ---------------------------------------------------------------------------
// Kernel 1: x [B,C,H,W] fp32 -> x_nhwc [B,H,W,C] bf16   (one block per (b,h))
// ---------------------------------------------------------------------------
__global__ void transpose_x(const float* __restrict__ x, uint16_t* __restrict__ xn) {
  const int h = blockIdx.x, b = blockIdx.y;
  __shared__ float tile[128][65];
  const int tid = threadIdx.x;
  #pragma unroll
  for (int it = 0; it < 32; ++it) {
    int idx = it * 256 + tid;
    int c = idx >> 6, w = idx & 63;
    tile[c][w] = x[(((b * 128 + c) * 64 + h) << 6) + w];  // coalesced in w
  }
  __syncthreads();
  uint32_t* out = (uint32_t*)(xn + ((size_t)(b * 64 + h) * 64) * 128);
  #pragma unroll
  for (int it = 0; it < 16; ++it) {
    int idx = it * 256 + tid;
    int w = idx >> 6, cd = idx & 63;            // cd = pair of channels
    uint32_t lo = f2bf(tile[cd * 2][w]);
    uint32_t hi = f2bf(tile[cd * 2 + 1][w]);
    out[w * 64 + cd] = lo | (hi << 16);          // coalesced in c
  }
}

// ---------------------------------------------------------------------------
// Kernel 2: convert 8 LSTM [512x128] + 4 conv [128x128] weight mats to bf16
// ---------------------------------------------------------------------------
struct PrepArgs { const float* s[12]; };

__global__ void prep_weights(PrepArgs a, uint16_t* __restrict__ wbuf,
                             uint16_t* __restrict__ wcbuf) {
  int idx = blockIdx.x * 256 + threadIdx.x;
  if (idx < 524288) {
    int m = idx >> 16;
    wbuf[idx] = f2bf(a.s[m][idx & 65535]);
  } else {
    int j = idx - 524288;
    if (j < 65536) {
      int m = j >> 14;
      wcbuf[j] = f2bf(a.s[8 + m][j & 16383]);
    }
  }
}

// ---------------------------------------------------------------------------
// Kernel 3: fused bidirectional LSTM over both axes.
//   grid (64, 4): blockIdx.y = dir {0:v_fwd, 1:v_bwd, 2:h_fwd, 3:h_bwd}
//   block 512 thr = 8 waves, 32 sequences/block, full time loop in-block.
//   All B-fragments (Wih + Whh) pinned in VGPRs (128 regs/thread).
// ---------------------------------------------------------------------------
__global__ __launch_bounds__(512, 2) void lstm_kernel(
    const uint16_t* __restrict__ xn,    // [PIXTOT][128] bf16 NHWC
    const uint16_t* __restrict__ wbuf,  // 8 x [512][128] bf16
    const float* __restrict__ bvf, const float* __restrict__ bvb,
    const float* __restrict__ bhf, const float* __restrict__ bhb,
    uint16_t* __restrict__ hbuf)        // 4 x [NSEQ*TLEN][128] bf16
{
  const int dir  = blockIdx.y;
  const int seq0 = blockIdx.x * 32;
  const int tid  = threadIdx.x;
  const int wv   = tid >> 6;
  const int lane = tid & 63;
  const int l15  = lane & 15;
  const int l4   = lane >> 4;
  const int mycol = wv * 16 + l15;       // channel 0..127 this lane owns in C/D
  const bool rev   = (dir & 1);
  const bool horiz = (dir >= 2);

  const uint16_t* wih = wbuf + (size_t)(2 * dir) * (512 * 128);
  const uint16_t* whh = wih + 512 * 128;
  const float* bias = (dir == 0) ? bvf : (dir == 1) ? bvb : (dir == 2) ? bhf : bhb;
  uint16_t* hout = hbuf + (size_t)dir * ((size_t)NSEQ * TLEN * 128);

  // B fragments: Wih/Whh are [4C][C] row-major = B^T; frag = 8 consecutive c.
  bf16x8 Bih[4][4], Bhh[4][4];           // [gate i/f/g/o][k-chunk]
  {
    const int base = mycol * 128 + l4 * 8;
    #pragma unroll
    for (int g = 0; g < 4; ++g)
      #pragma unroll
      for (int kc = 0; kc < 4; ++kc) {
        Bih[g][kc] = *(const bf16x8*)(wih + base + g * (128 * 128) + kc * 32);
        Bhh[g][kc] = *(const bf16x8*)(whh + base + g * (128 * 128) + kc * 32);
      }
  }
  float bia[4];
  #pragma unroll
  for (int g = 0; g < 4; ++g) bia[g] = bias[mycol + 128 * g];

  // h exchange buffer, double-buffered. stride 136 keeps b128 reads 16B-aligned
  // and spreads banks evenly (68 dwords/row -> 4*seq bank rotation).
  __shared__ __attribute__((aligned(16))) uint16_t hlds[2][32][136];
  for (int i = tid; i < 2 * 32 * 136; i += 512) ((uint16_t*)hlds)[i] = 0;
  __syncthreads();

  // x addressing: element offset of (seq, t=0, c=0) in xn, lane-specific c later
  int xbase[2];
  #pragma unroll
  for (int mt = 0; mt < 2; ++mt) {
    int seq = seq0 + mt * 16 + l15;
    xbase[mt] = horiz ? (((seq >> 6) * 4096 + (seq & 63)) * 128)
                      : (seq * (64 * 128));
  }
  const int tstride = horiz ? (64 * 128) : 128;

  float cst[2][4];
  #pragma unroll
  for (int mt = 0; mt < 2; ++mt)
    #pragma unroll
    for (int r = 0; r < 4; ++r) cst[mt][r] = 0.f;

  const f32x4 vzero = {0.f, 0.f, 0.f, 0.f};

  for (int step = 0; step < 64; ++step) {
    const int t = rev ? (63 - step) : step;
    const int cur = step & 1, nxt = cur ^ 1;

    f32x4 acc[2][4];
    #pragma unroll
    for (int mt = 0; mt < 2; ++mt)
      #pragma unroll
      for (int g = 0; g < 4; ++g) acc[mt][g] = vzero;

    #pragma unroll
    for (int kc = 0; kc < 4; ++kc) {
      bf16x8 ax[2], ah[2];
      #pragma unroll
      for (int mt = 0; mt < 2; ++mt) {
        ax[mt] = *(const bf16x8*)(xn + xbase[mt] + t * tstride + kc * 32 + l4 * 8);
        ah[mt] = *(const bf16x8*)(&hlds[cur][mt * 16 + l15][kc * 32 + l4 * 8]);
      }
      #pragma unroll
      for (int mt = 0; mt < 2; ++mt)
        #pragma unroll
        for (int g = 0; g < 4; ++g) {
          acc[mt][g] = __builtin_amdgcn_mfma_f32_16x16x32_bf16(ax[mt], Bih[g][kc], acc[mt][g], 0, 0, 0);
          acc[mt][g] = __builtin_amdgcn_mfma_f32_16x16x32_bf16(ah[mt], Bhh[g][kc], acc[mt][g], 0, 0, 0);
        }
    }

    // gate math. D layout: col = lane&15 (= channel mycol), row = l4*4+r (= seq)
    #pragma unroll
    for (int mt = 0; mt < 2; ++mt)
      #pragma unroll
      for (int r = 0; r < 4; ++r) {
        float zi = acc[mt][0][r] + bia[0];
        float zf = acc[mt][1][r] + bia[1];
        float zg = acc[mt][2][r] + bia[2];
        float zo = acc[mt][3][r] + bia[3];
        float c = sigf(zf) * cst[mt][r] + sigf(zi) * tanh_(zg);
        cst[mt][r] = c;
        float h = sigf(zo) * tanh_(c);
        hlds[nxt][mt * 16 + l4 * 4 + r][mycol] = f2bf(h);
      }
    __syncthreads();

    // coalesced store of h(t) to global (read from completed buffer)
    {
      int sq = tid >> 4, c8 = (tid & 15) * 8;
      bf16x8 v = *(const bf16x8*)(&hlds[nxt][sq][c8]);
      *(bf16x8*)(hout + ((size_t)(seq0 + sq) * 64 + t) * 128 + c8) = v;
    }
  }
}

// ---------------------------------------------------------------------------
// Kernel 4: 1x1 conv = [128 pixels x 128 ch] x [128 ch x 128 out] MFMA GEMM.
//   grid (1024, 4): blockIdx.y = output {0:down, 1:up, 2:right, 3:left}
//   Epilogue transposes D through XOR-swizzled LDS for coalesced fp32 stores.
// ---------------------------------------------------------------------------
__global__ __launch_bounds__(256, 2) void conv_kernel(
    const uint16_t* __restrict__ hbuf, const uint16_t* __restrict__ wc,
    const float* __restrict__ b_down, const float* __restrict__ b_up,
    const float* __restrict__ b_right, const float* __restrict__ b_left,
    float* __restrict__ out)
{
  const int d   = blockIdx.y;
  const int P0  = blockIdx.x * 128;
  const int tid = threadIdx.x;
  const int wv = tid >> 6, lane = tid & 63, l15 = lane & 15, l4 = lane >> 4;

  const int lstm_dir = (d == 0) ? 1 : (d == 1) ? 0 : d;   // down<-v_bwd, up<-v_fwd
  const uint16_t* hb = hbuf + (size_t)lstm_dir * ((size_t)NSEQ * TLEN * 128);
  const uint16_t* w  = wc + d * (128 * 128);
  const float* bias = (d == 0) ? b_down : (d == 1) ? b_up : (d == 2) ? b_right : b_left;
  float* outp = out + (size_t)d * OUTSZ;

  bf16x8 Bf[2][4];
  float bc[2];
  #pragma unroll
  for (int j = 0; j < 2; ++j) {
    int o = (2 * wv + j) * 16 + l15;
    bc[j] = bias[o];
    #pragma unroll
    for (int kc = 0; kc < 4; ++kc)
      Bf[j][kc] = *(const bf16x8*)(w + o * 128 + kc * 32 + l4 * 8);
  }

  const f32x4 vzero = {0.f, 0.f, 0.f, 0.f};
  f32x4 acc[8][2];
  #pragma unroll
  for (int mt = 0; mt < 8; ++mt) { acc[mt][0] = vzero; acc[mt][1] = vzero; }

  #pragma unroll
  for (int kc = 0; kc < 4; ++kc) {
    bf16x8 A[8];
    #pragma unroll
    for (int mt = 0; mt < 8; ++mt) {
      int p = P0 + mt * 16 + l15;
      A[mt] = *(const bf16x8*)(hb + (size_t)p * 128 + kc * 32 + l4 * 8);
    }
    #pragma unroll
    for (int mt = 0; mt < 8; ++mt)
      #pragma unroll
      for (int j = 0; j < 2; ++j)
        acc[mt][j] = __builtin_amdgcn_mfma_f32_16x16x32_bf16(A[mt], Bf[j][kc], acc[mt][j], 0, 0, 0);
  }

  // LDS transpose [o][s], 64KB, XOR swizzle on 4-dword chunks to avoid the
  // 16-way conflicts a power-of-2 row stride would cause on the tile writes.
  __shared__ __attribute__((aligned(16))) float olds[128][128];
  #pragma unroll
  for (int mt = 0; mt < 8; ++mt)
    #pragma unroll
    for (int j = 0; j < 2; ++j) {
      int o = (2 * wv + j) * 16 + l15;
      f32x4 v = acc[mt][j] + bc[j];
      int chunk = mt * 4 + l4;                 // s>>2
      int phys = chunk ^ (o & 31);
      *(f32x4*)(&olds[o][phys << 2]) = v;
    }
  __syncthreads();

  const int bb = P0 >> 12, s0 = P0 & 4095;
  float* obase = outp + ((size_t)bb * 128) * 4096 + s0;
  #pragma unroll
  for (int it = 0; it < 16; ++it) {
    int flat = (it * 256 + tid) * 4;
    int o = flat >> 7, s = flat & 127;
    int phys = (s >> 2) ^ (o & 31);
    f32x4 v = *(const f32x4*)(&olds[o][phys << 2]);
    *(f32x4*)(obase + (size_t)o * 4096 + s) = v;   // coalesced fp32 rows
  }
}

// ---------------------------------------------------------------------------
extern "C" void kernel_launch(void* const* d_in, const int* in_sizes, int n_in,
                              void* d_out, int out_size, void* d_ws, size_t ws_size,
                              hipStream_t stream) {
  const float* x = (const float*)d_in[0];
  uint16_t* ws    = (uint16_t*)d_ws;
  uint16_t* xn    = ws;                      // 16,777,216 bf16
  uint16_t* wbuf  = xn + 16777216;           // 524,288 bf16 (8 LSTM mats)
  uint16_t* wcbuf = wbuf + 524288;           // 65,536 bf16 (4 conv mats)
  uint16_t* hbuf  = wcbuf + 65536;           // 4 * 16,777,216 bf16

  transpose_x<<<dim3(64, 32), 256, 0, stream>>>(x, xn);

  PrepArgs pa;
  const int widx[12] = {1, 2, 4, 5, 7, 8, 10, 11, 13, 15, 17, 19};
  for (int i = 0; i < 12; ++i) pa.s[i] = (const float*)d_in[widx[i]];
  prep_weights<<<2304, 256, 0, stream>>>(pa, wbuf, wcbuf);

  lstm_kernel<<<dim3(64, 4), 512, 0, stream>>>(
      xn, wbuf,
      (const float*)d_in[3], (const float*)d_in[6],
      (const float*)d_in[9], (const float*)d_in[12],
      hbuf);

  conv_kernel<<<dim3(1024, 4), 256, 0, stream>>>(
      hbuf, wcbuf,
      (const float*)d_in[14], (const float*)d_in[16],
      (const float*)d_in[18], (const float*)d_in[20],
      (float*)d_out);
}

// Round 2
// 601.343 us; speedup vs baseline: 1.0460x; 1.0460x over previous
//
#include <hip/hip_runtime.h>
#include <stdint.h>

#define OUTSZ  (32*128*64*64)  // 16777216 elements per output tensor

typedef short bf16x8 __attribute__((ext_vector_type(8)));  // 8 bf16 = 4 VGPRs
typedef float f32x4  __attribute__((ext_vector_type(4)));

__device__ __forceinline__ uint16_t f2bf(float f) {
  union { float f; uint32_t u; } v; v.f = f;
  uint32_t u = v.u;
  u += 0x7fffu + ((u >> 16) & 1u);   // round-to-nearest-even
  return (uint16_t)(u >> 16);
}

__device__ __forceinline__ float sigf(float x) {
  return __builtin_amdgcn_rcpf(1.f + __expf(-x));
}
__device__ __forceinline__ float tanh_(float x) {
  float ax = fabsf(x);
  float e  = __expf(-2.f * ax);
  float t  = (1.f - e) * __builtin_amdgcn_rcpf(1.f + e);
  return copysignf(t, x);
}

// ---------------------------------------------------------------------------
// Kernel 1: x [B,C,H,W] fp32 -> x_nhwc [B,H,W,C] bf16   (one block per (b,h))
// ---------------------------------------------------------------------------
__global__ void transpose_x(const float* __restrict__ x, uint16_t* __restrict__ xn) {
  const int h = blockIdx.x, b = blockIdx.y;
  __shared__ float tile[128][65];
  const int tid = threadIdx.x;
  #pragma unroll
  for (int it = 0; it < 32; ++it) {
    int idx = it * 256 + tid;
    int c = idx >> 6, w = idx & 63;
    tile[c][w] = x[(((b * 128 + c) * 64 + h) << 6) + w];  // coalesced in w
  }
  __syncthreads();
  uint32_t* out = (uint32_t*)(xn + ((size_t)(b * 64 + h) * 64) * 128);
  #pragma unroll
  for (int it = 0; it < 16; ++it) {
    int idx = it * 256 + tid;
    int w = idx >> 6, cd = idx & 63;            // cd = pair of channels
    uint32_t lo = f2bf(tile[cd * 2][w]);
    uint32_t hi = f2bf(tile[cd * 2 + 1][w]);
    out[w * 64 + cd] = lo | (hi << 16);          // coalesced in c
  }
}

// ---------------------------------------------------------------------------
// Kernel 2: convert 8 LSTM [512x128] + 4 conv [128x128] weight mats to bf16
// ---------------------------------------------------------------------------
struct PrepArgs { const float* s[12]; };

__global__ void prep_weights(PrepArgs a, uint16_t* __restrict__ wbuf,
                             uint16_t* __restrict__ wcbuf) {
  int idx = blockIdx.x * 256 + threadIdx.x;
  if (idx < 524288) {
    int m = idx >> 16;
    wbuf[idx] = f2bf(a.s[m][idx & 65535]);
  } else {
    int j = idx - 524288;
    if (j < 65536) {
      int m = j >> 14;
      wcbuf[j] = f2bf(a.s[8 + m][j & 16383]);
    }
  }
}

// ---------------------------------------------------------------------------
// Kernel 3: fused bidirectional LSTM over both axes.
//   grid (64, 4): blockIdx.y = dir {0:v_fwd, 1:v_bwd, 2:h_fwd, 3:h_bwd}
//   512 thr = 8 waves, 32 sequences/block, full time loop in-block.
//   h lives in an 8-slot LDS ring; one slot/step is lazily dumped to global
//   (7-step lag) so the pre-barrier vmcnt(0) drain only sees an 8KB store
//   issued a full step earlier. x(t+1) fragments are software-prefetched.
// ---------------------------------------------------------------------------
__global__ __launch_bounds__(512, 2) void lstm_kernel(
    const uint16_t* __restrict__ xn,    // [PIXTOT][128] bf16 NHWC
    const uint16_t* __restrict__ wbuf,  // 8 x [512][128] bf16
    const float* __restrict__ bvf, const float* __restrict__ bvb,
    const float* __restrict__ bhf, const float* __restrict__ bhb,
    uint16_t* __restrict__ hbuf)        // 4 x [2048*64][128] bf16
{
  const int dir  = blockIdx.y;
  const int seq0 = blockIdx.x * 32;
  const int tid  = threadIdx.x;
  const int wv   = tid >> 6;
  const int lane = tid & 63;
  const int l15  = lane & 15;
  const int l4   = lane >> 4;
  const int mycol = wv * 16 + l15;       // channel 0..127 this lane owns in C/D
  const bool rev   = (dir & 1);
  const bool horiz = (dir >= 2);

  const uint16_t* wih = wbuf + (size_t)(2 * dir) * (512 * 128);
  const uint16_t* whh = wih + 512 * 128;
  const float* bias = (dir == 0) ? bvf : (dir == 1) ? bvb : (dir == 2) ? bhf : bhb;
  uint16_t* hout = hbuf + (size_t)dir * ((size_t)2048 * 64 * 128);

  // B fragments: Wih/Whh are [4C][C] row-major = B^T; frag = 8 consecutive c.
  bf16x8 Bih[4][4], Bhh[4][4];           // [gate i/f/g/o][k-chunk]
  {
    const int base = mycol * 128 + l4 * 8;
    #pragma unroll
    for (int g = 0; g < 4; ++g)
      #pragma unroll
      for (int kc = 0; kc < 4; ++kc) {
        Bih[g][kc] = *(const bf16x8*)(wih + base + g * (128 * 128) + kc * 32);
        Bhh[g][kc] = *(const bf16x8*)(whh + base + g * (128 * 128) + kc * 32);
      }
  }
  float bia[4];
  #pragma unroll
  for (int g = 0; g < 4; ++g) bia[g] = bias[mycol + 128 * g];

  // 8-slot h ring. Row stride 136 u16 = 272B (16B aligned). 16B chunks are
  // XOR-swizzled by (row>>2)&3 -> scalar gate writes are bank-conflict-free.
  __shared__ __attribute__((aligned(16))) uint16_t ring[8][32][136];
  {
    uint32_t* p = (uint32_t*)&ring[7][0][0];   // only slot 7 is read at step 0
    for (int i = tid; i < 2176; i += 512) p[i] = 0;
  }
  __syncthreads();

  int xbase[2];
  #pragma unroll
  for (int mt = 0; mt < 2; ++mt) {
    int seq = seq0 + mt * 16 + l15;
    xbase[mt] = horiz ? (((seq >> 6) * 4096 + (seq & 63)) * 128)
                      : (seq * (64 * 128));
  }
  const int tstride = horiz ? (64 * 128) : 128;

  float cst[2][4];
  #pragma unroll
  for (int mt = 0; mt < 2; ++mt)
    #pragma unroll
    for (int r = 0; r < 4; ++r) cst[mt][r] = 0.f;

  // lazy-dump lane mapping: 512 thr cover one slot (32 rows x 16 chunks)
  const int drow   = tid >> 4;          // 0..31
  const int dchunk = tid & 15;
  const int dpc8   = dchunk ^ ((drow >> 2) & 3);

  auto dump_slot = [&](int g, int s) {
    bf16x8 v = *(const bf16x8*)(&ring[s][drow][dpc8 * 8]);
    int stepl = g * 8 + s;
    int t = rev ? 63 - stepl : stepl;
    *(bf16x8*)(hout + ((size_t)(seq0 + drow) * 64 + t) * 128 + dchunk * 8) = v;
  };

  const int swz = (l15 >> 2) & 3;
  const f32x4 vzero = {0.f, 0.f, 0.f, 0.f};

  auto do_step = [&](int step, bf16x8 (&axc)[2][4], bf16x8 (&axn)[2][4]) {
    // --- prefetch x(t+1) (issued first; completes during gate math) ---
    const int tn_l = (step < 63) ? step + 1 : 63;
    const int tn   = rev ? 63 - tn_l : tn_l;
    #pragma unroll
    for (int mt = 0; mt < 2; ++mt)
      #pragma unroll
      for (int kc = 0; kc < 4; ++kc)
        axn[mt][kc] = *(const bf16x8*)(xn + xbase[mt] + tn * tstride + kc * 32 + l4 * 8);

    // --- lazy dump: slot (step+1)&7 of group ((step+1)>>3)-1.
    // Written at 8g+s, read here at 8g+s+7, rewritten at 8g+s+8 (post-barrier).
    if (step >= 7) dump_slot(((step + 1) >> 3) - 1, (step + 1) & 7);

    const int prev = (step + 7) & 7;
    f32x4 acc[2][4];
    #pragma unroll
    for (int mt = 0; mt < 2; ++mt)
      #pragma unroll
      for (int g = 0; g < 4; ++g) acc[mt][g] = vzero;

    #pragma unroll
    for (int kc = 0; kc < 4; ++kc) {
      bf16x8 ah[2];
      #pragma unroll
      for (int mt = 0; mt < 2; ++mt)
        ah[mt] = *(const bf16x8*)(&ring[prev][mt * 16 + l15][((kc * 4 + l4) ^ swz) * 8]);
      #pragma unroll
      for (int mt = 0; mt < 2; ++mt)
        #pragma unroll
        for (int g = 0; g < 4; ++g) {
          acc[mt][g] = __builtin_amdgcn_mfma_f32_16x16x32_bf16(axc[mt][kc], Bih[g][kc], acc[mt][g], 0, 0, 0);
          acc[mt][g] = __builtin_amdgcn_mfma_f32_16x16x32_bf16(ah[mt],      Bhh[g][kc], acc[mt][g], 0, 0, 0);
        }
    }

    // gate math. D layout: col = lane&15 (= channel mycol), row = l4*4+r (= seq)
    const int slot = step & 7;
    #pragma unroll
    for (int mt = 0; mt < 2; ++mt)
      #pragma unroll
      for (int r = 0; r < 4; ++r) {
        float zi = acc[mt][0][r] + bia[0];
        float zf = acc[mt][1][r] + bia[1];
        float zg = acc[mt][2][r] + bia[2];
        float zo = acc[mt][3][r] + bia[3];
        float c = sigf(zf) * cst[mt][r] + sigf(zi) * tanh_(zg);
        cst[mt][r] = c;
        float h = sigf(zo) * tanh_(c);
        int row = mt * 16 + l4 * 4 + r;
        ring[slot][row][((mycol >> 3) ^ l4) * 8 + (mycol & 7)] = f2bf(h);
      }
    __syncthreads();
  };

  // preload x(t0), then run 64 steps with register double-buffered x
  bf16x8 axA[2][4], axB[2][4];
  {
    const int t0 = rev ? 63 : 0;
    #pragma unroll
    for (int mt = 0; mt < 2; ++mt)
      #pragma unroll
      for (int kc = 0; kc < 4; ++kc)
        axA[mt][kc] = *(const bf16x8*)(xn + xbase[mt] + t0 * tstride + kc * 32 + l4 * 8);
  }
  for (int s2 = 0; s2 < 64; s2 += 2) {
    do_step(s2,     axA, axB);
    do_step(s2 + 1, axB, axA);
  }
  // remaining slots of the last group (reads fenced by the final barrier)
  #pragma unroll
  for (int s = 1; s < 8; ++s) dump_slot(7, s);
}

// ---------------------------------------------------------------------------
// Kernel 4: 1x1 conv = [128 pixels x 128 ch] x [128 ch x 128 out] MFMA GEMM.
//   grid (1024, 4): blockIdx.y = output {0:down, 1:up, 2:right, 3:left}
//   Two-pass epilogue through a 33KB LDS tile (64 o-rows per pass) -> more
//   blocks/CU than the old 64KB single-pass transpose.
// ---------------------------------------------------------------------------
__global__ __launch_bounds__(256, 2) void conv_kernel(
    const uint16_t* __restrict__ hbuf, const uint16_t* __restrict__ wc,
    const float* __restrict__ b_down, const float* __restrict__ b_up,
    const float* __restrict__ b_right, const float* __restrict__ b_left,
    float* __restrict__ out)
{
  const int d   = blockIdx.y;
  const int P0  = blockIdx.x * 128;
  const int tid = threadIdx.x;
  const int wv = tid >> 6, lane = tid & 63, l15 = lane & 15, l4 = lane >> 4;

  const int lstm_dir = (d == 0) ? 1 : (d == 1) ? 0 : d;   // down<-v_bwd, up<-v_fwd
  const uint16_t* hb = hbuf + (size_t)lstm_dir * ((size_t)2048 * 64 * 128);
  const uint16_t* w  = wc + d * (128 * 128);
  const float* bias = (d == 0) ? b_down : (d == 1) ? b_up : (d == 2) ? b_right : b_left;
  float* outp = out + (size_t)d * OUTSZ;

  bf16x8 Bf[2][4];
  float bc[2];
  #pragma unroll
  for (int j = 0; j < 2; ++j) {
    int o = (2 * wv + j) * 16 + l15;
    bc[j] = bias[o];
    #pragma unroll
    for (int kc = 0; kc < 4; ++kc)
      Bf[j][kc] = *(const bf16x8*)(w + o * 128 + kc * 32 + l4 * 8);
  }

  const f32x4 vzero = {0.f, 0.f, 0.f, 0.f};
  f32x4 acc[8][2];
  #pragma unroll
  for (int mt = 0; mt < 8; ++mt) { acc[mt][0] = vzero; acc[mt][1] = vzero; }

  #pragma unroll
  for (int kc = 0; kc < 4; ++kc) {
    bf16x8 A[8];
    #pragma unroll
    for (int mt = 0; mt < 8; ++mt) {
      int p = P0 + mt * 16 + l15;
      A[mt] = *(const bf16x8*)(hb + (size_t)p * 128 + kc * 32 + l4 * 8);
    }
    #pragma unroll
    for (int mt = 0; mt < 8; ++mt)
      #pragma unroll
      for (int j = 0; j < 2; ++j)
        acc[mt][j] = __builtin_amdgcn_mfma_f32_16x16x32_bf16(A[mt], Bf[j][kc], acc[mt][j], 0, 0, 0);
  }

  // Two-pass LDS transpose: pass j handles o-rows (2wv+j)*16+l15 (64 rows).
  // Row stride 132 dwords (%32==4) spreads banks; b128 ops stay width-bound.
  __shared__ __attribute__((aligned(16))) float olds[64][132];
  const int bb = P0 >> 12, s0 = P0 & 4095;
  float* obase = outp + ((size_t)bb * 128) * 4096 + s0;

  #pragma unroll
  for (int j = 0; j < 2; ++j) {
    if (j) __syncthreads();
    #pragma unroll
    for (int mt = 0; mt < 8; ++mt) {
      f32x4 v = acc[mt][j] + bc[j];
      *(f32x4*)(&olds[wv * 16 + l15][(mt * 4 + l4) * 4]) = v;
    }
    __syncthreads();
    #pragma unroll
    for (int it = 0; it < 8; ++it) {
      int flat = (it * 256 + tid) * 4;
      int ol = flat >> 7, s = flat & 127;
      int o = (ol >> 4) * 32 + j * 16 + (ol & 15);
      f32x4 v = *(const f32x4*)(&olds[ol][s]);
      *(f32x4*)(obase + (size_t)o * 4096 + s) = v;   // coalesced fp32 rows
    }
  }
}

// ---------------------------------------------------------------------------
extern "C" void kernel_launch(void* const* d_in, const int* in_sizes, int n_in,
                              void* d_out, int out_size, void* d_ws, size_t ws_size,
                              hipStream_t stream) {
  const float* x = (const float*)d_in[0];
  uint16_t* ws    = (uint16_t*)d_ws;
  uint16_t* xn    = ws;                      // 16,777,216 bf16
  uint16_t* wbuf  = xn + 16777216;           // 524,288 bf16 (8 LSTM mats)
  uint16_t* wcbuf = wbuf + 524288;           // 65,536 bf16 (4 conv mats)
  uint16_t* hbuf  = wcbuf + 65536;           // 4 * 16,777,216 bf16

  transpose_x<<<dim3(64, 32), 256, 0, stream>>>(x, xn);

  PrepArgs pa;
  const int widx[12] = {1, 2, 4, 5, 7, 8, 10, 11, 13, 15, 17, 19};
  for (int i = 0; i < 12; ++i) pa.s[i] = (const float*)d_in[widx[i]];
  prep_weights<<<2304, 256, 0, stream>>>(pa, wbuf, wcbuf);

  lstm_kernel<<<dim3(64, 4), 512, 0, stream>>>(
      xn, wbuf,
      (const float*)d_in[3], (const float*)d_in[6],
      (const float*)d_in[9], (const float*)d_in[12],
      hbuf);

  conv_kernel<<<dim3(1024, 4), 256, 0, stream>>>(
      hbuf, wcbuf,
      (const float*)d_in[14], (const float*)d_in[16],
      (const float*)d_in[18], (const float*)d_in[20],
      (float*)d_out);
}